// Round 1
// baseline (1139.048 us; speedup 1.0000x reference)
//
#include <hip/hip_runtime.h>
#include <stdint.h>

// Problem constants (from reference): N=500000, D_IN=128, R=256, D_OUT=64, U=10000
#define N_ROWS 500000
#define U_DIM 10000
#define EPSV 1e-8f

typedef __attribute__((ext_vector_type(8))) short bf16x8;   // 8 bf16 = 4 VGPRs
typedef __attribute__((ext_vector_type(4))) float f32x4;    // MFMA 16x16 accumulator

// f32 -> bf16 round-to-nearest-even (manual, 3 VALU ops, finite inputs only)
__device__ __forceinline__ short f2bf(float f) {
  unsigned u = __float_as_uint(f);
  u += 0x7fffu + ((u >> 16) & 1u);
  return (short)(u >> 16);
}
__device__ __forceinline__ float bf2f(short s) {
  return __uint_as_float(((unsigned)(unsigned short)s) << 16);
}

// d_ws layout (shorts):
//   Wmu0t  [256][128] @ 0       (B^T for layer0 mean GEMM:  Wmu0t[c][k] = W_mu0[k][c])
//   Wvar0t [256][128] @ 32768   (bf16(exp(W_lv0)) transposed)
//   Wmu1t  [64][256]  @ 65536
//   A1t    [64][256]  @ 81920   (bf16(W_mu1^2 + exp(W_lv1)) transposed)
//   Wvar1t [64][256]  @ 98304   -> total 114688 shorts = 224 KB
__global__ void prep_weights(const float* __restrict__ Wmu0,
                             const float* __restrict__ Wlv0,
                             const float* __restrict__ Wmu1,
                             const float* __restrict__ Wlv1,
                             short* __restrict__ wgt) {
  int i = blockIdx.x * blockDim.x + threadIdx.x;
  if (i < 32768) {                       // layer-0 weights: (k,c) with c fastest
    int c = i & 255, k = i >> 8;
    float mu = Wmu0[k * 256 + c];
    float ev = __expf(Wlv0[k * 256 + c]);
    wgt[c * 128 + k]         = f2bf(mu);
    wgt[32768 + c * 128 + k] = f2bf(ev);
  } else if (i < 49152) {                // layer-1 weights: (j,o) with o fastest
    int i2 = i - 32768;
    int o = i2 & 63, j = i2 >> 6;
    float mu = Wmu1[j * 64 + o];
    float ev = __expf(Wlv1[j * 64 + o]);
    wgt[65536 + o * 256 + j] = f2bf(mu);
    wgt[81920 + o * 256 + j] = f2bf(mu * mu + ev);
    wgt[98304 + o * 256 + j] = f2bf(ev);
  }
}

// Fused 2-layer VB kernel. One wave owns one 16-row tile; zero __syncthreads.
// Block = 128 threads (2 waves). Grid = N/32 = 15625 (exact).
// LDS per block: 2 waves * 2 arrays * 16*264 shorts = 33 KB -> 4 blocks/CU.
__global__ __launch_bounds__(128, 2) void vb_fused(
    const float* __restrict__ X, const int* __restrict__ Xidx,
    const short* __restrict__ wgt, float* __restrict__ out) {
  __shared__ short ldsM[2][16 * 264];   // stride 264 shorts: 16B-aligned rows, spreads banks
  __shared__ short ldsV[2][16 * 264];

  const int tid  = threadIdx.x;
  const int w    = tid >> 6;            // wave in block
  const int lane = tid & 63;
  const int n    = lane & 15;           // MFMA row (A) / col (B,D)
  const int q    = lane >> 4;           // MFMA k-octet / D row-quad
  const int tile = blockIdx.x * 2 + w;
  const int row0 = tile * 16;

  const short* Wmu0t  = wgt;
  const short* Wvar0t = wgt + 32768;
  const short* Wmu1t  = wgt + 65536;
  const short* A1t    = wgt + 81920;
  const short* Wvar1t = wgt + 98304;

  const f32x4 zf4 = {0.f, 0.f, 0.f, 0.f};

  // ---------------- layer 0: M0 = X@Wmu0, V0 = X^2@exp(Wlv0), 16 rows x 256 cols
  f32x4 accm[16], accv[16];
#pragma unroll
  for (int t = 0; t < 16; ++t) { accm[t] = zf4; accv[t] = zf4; }

  const float* xrow = X + (size_t)(row0 + n) * 128;
#pragma unroll
  for (int kt = 0; kt < 128; kt += 32) {
    float xf[8];
    *(float4*)&xf[0] = *(const float4*)&xrow[kt + q * 8];
    *(float4*)&xf[4] = *(const float4*)&xrow[kt + q * 8 + 4];
    bf16x8 a_m, a_sq;
#pragma unroll
    for (int u = 0; u < 8; ++u) {
      a_m[u]  = f2bf(xf[u]);
      a_sq[u] = f2bf(xf[u] * xf[u]);
    }
#pragma unroll
    for (int ct = 0; ct < 16; ++ct) {
      const int wb = (ct * 16 + n) * 128 + kt + q * 8;
      bf16x8 bm = *(const bf16x8*)&Wmu0t[wb];
      bf16x8 bv = *(const bf16x8*)&Wvar0t[wb];
      accm[ct] = __builtin_amdgcn_mfma_f32_16x16x32_bf16(a_m,  bm, accm[ct], 0, 0, 0);
      accv[ct] = __builtin_amdgcn_mfma_f32_16x16x32_bf16(a_sq, bv, accv[ct], 0, 0, 0);
    }
  }

  // ReLU-gate (gate = M0 > 0) and spill to wave-private LDS as bf16.
  // C/D layout: col = lane&15 (-> c), row = q*4 + reg.
#pragma unroll
  for (int ct = 0; ct < 16; ++ct) {
    const int c = ct * 16 + n;
#pragma unroll
    for (int reg = 0; reg < 4; ++reg) {
      float m = accm[ct][reg], v = accv[ct][reg];
      if (!(m > 0.f)) { m = 0.f; v = 0.f; }
      const int row = q * 4 + reg;
      ldsM[w][row * 264 + c] = f2bf(m);
      ldsV[w][row * 264 + c] = f2bf(v);
    }
  }
  // Wave-private LDS: same-wave RAW handled by compiler waitcnt; no barrier needed.

  // ---------------- layer 1: 16 rows x 64 cols, contraction over j=0..255
  f32x4 accm1[4], accv1[4];
#pragma unroll
  for (int t = 0; t < 4; ++t) { accm1[t] = zf4; accv1[t] = zf4; }

#pragma unroll
  for (int jt = 0; jt < 256; jt += 32) {
    // A layout: row = lane&15, k = q*8 + j -> contiguous 16B per lane
    bf16x8 am = *(const bf16x8*)&ldsM[w][n * 264 + jt + q * 8];
    bf16x8 av = *(const bf16x8*)&ldsV[w][n * 264 + jt + q * 8];
    bf16x8 asq;
#pragma unroll
    for (int u = 0; u < 8; ++u) {
      float f = bf2f(am[u]);
      asq[u] = f2bf(f * f);
    }
#pragma unroll
    for (int ct = 0; ct < 4; ++ct) {
      const int wb = (ct * 16 + n) * 256 + jt + q * 8;
      bf16x8 b1 = *(const bf16x8*)&Wmu1t[wb];
      bf16x8 b2 = *(const bf16x8*)&A1t[wb];
      bf16x8 b3 = *(const bf16x8*)&Wvar1t[wb];
      accm1[ct] = __builtin_amdgcn_mfma_f32_16x16x32_bf16(am,  b1, accm1[ct], 0, 0, 0);
      accv1[ct] = __builtin_amdgcn_mfma_f32_16x16x32_bf16(av,  b2, accv1[ct], 0, 0, 0);
      accv1[ct] = __builtin_amdgcn_mfma_f32_16x16x32_bf16(asq, b3, accv1[ct], 0, 0, 0);
    }
  }

  // ---------------- epilogue: inv_v / m*inv_v, run-aggregated segment atomics.
  // Lane owns rows q*4..q*4+3 (consecutive, idx sorted) for col o = ct*16+n.
  int4 idx4 = *(const int4*)&Xidx[row0 + q * 4];
  int uid[4] = {idx4.x, idx4.y, idx4.z, idx4.w};
  float* meanp = out;                      // accumulates sum(m*inv_v)
  float* varp  = out + U_DIM * 64;         // accumulates sum(inv_v)
#pragma unroll
  for (int ct = 0; ct < 4; ++ct) {
    const int o = ct * 16 + n;
    float sm = 0.f, sv = 0.f;
    int cur = uid[0];
#pragma unroll
    for (int reg = 0; reg < 4; ++reg) {
      float v1 = fmaxf(accv1[ct][reg], EPSV);
      float inv = 1.0f / v1;
      float mi  = accm1[ct][reg] * inv;
      if (uid[reg] != cur) {
        atomicAdd(&meanp[cur * 64 + o], sm);
        atomicAdd(&varp[cur * 64 + o], sv);
        sm = 0.f; sv = 0.f; cur = uid[reg];
      }
      sm += mi; sv += inv;
    }
    atomicAdd(&meanp[cur * 64 + o], sm);
    atomicAdd(&varp[cur * 64 + o], sv);
  }
}

// emb_var = 1/(sum_inv + eps); emb_mean = sum_m_inv * emb_var  (in place)
__global__ void finalize(float* __restrict__ out) {
  int i = blockIdx.x * blockDim.x + threadIdx.x;
  if (i < U_DIM * 64) {
    float s = out[U_DIM * 64 + i];
    float var = 1.0f / (s + EPSV);
    out[U_DIM * 64 + i] = var;
    out[i] = out[i] * var;
  }
}

extern "C" void kernel_launch(void* const* d_in, const int* in_sizes, int n_in,
                              void* d_out, int out_size, void* d_ws, size_t ws_size,
                              hipStream_t stream) {
  (void)in_sizes; (void)n_in; (void)out_size; (void)ws_size;
  const float* X    = (const float*)d_in[0];
  const int*   Xidx = (const int*)d_in[1];
  const float* Wmu0 = (const float*)d_in[2];
  const float* Wlv0 = (const float*)d_in[3];
  const float* Wmu1 = (const float*)d_in[4];
  const float* Wlv1 = (const float*)d_in[5];
  float* out = (float*)d_out;
  short* wgt = (short*)d_ws;   // needs 224 KB of workspace

  // zero the segment accumulators (harness poisons d_out with 0xAA each launch)
  hipMemsetAsync(d_out, 0, (size_t)U_DIM * 64 * 2 * sizeof(float), stream);
  prep_weights<<<192, 256, 0, stream>>>(Wmu0, Wlv0, Wmu1, Wlv1, wgt);
  vb_fused<<<N_ROWS / 32, 128, 0, stream>>>(X, Xidx, wgt, out);
  finalize<<<(U_DIM * 64 + 255) / 256, 256, 0, stream>>>(out);
}

// Round 2
// 783.892 us; speedup vs baseline: 1.4531x; 1.4531x over previous
//
#include <hip/hip_runtime.h>
#include <stdint.h>

// Problem constants: N=500000, D_IN=128, R=256, D_OUT=64, U=10000
#define N_ROWS 500000
#define U_DIM 10000
#define EPSV 1e-8f

typedef __attribute__((ext_vector_type(8))) short bf16x8;   // 8 bf16 = 4 VGPRs
typedef __attribute__((ext_vector_type(4))) float f32x4;    // MFMA 16x16 accumulator

__device__ __forceinline__ short f2bf(float f) {
  unsigned u = __float_as_uint(f);
  u += 0x7fffu + ((u >> 16) & 1u);
  return (short)(u >> 16);
}
__device__ __forceinline__ float bf2f(short s) {
  return __uint_as_float(((unsigned)(unsigned short)s) << 16);
}

// d_ws layout (shorts):
//   Wmu0t  [256][128] @ 0       Wmu0t[c][k] = bf16(W_mu0[k][c])
//   Wvar0t [256][128] @ 32768   bf16(exp(W_lv0)) transposed
//   Wmu1t  [64][256]  @ 65536
//   A1t    [64][256]  @ 81920   bf16(W_mu1^2 + exp(W_lv1)) transposed
//   Wvar1t [64][256]  @ 98304   -> 224 KB total
__global__ void prep_weights(const float* __restrict__ Wmu0,
                             const float* __restrict__ Wlv0,
                             const float* __restrict__ Wmu1,
                             const float* __restrict__ Wlv1,
                             short* __restrict__ wgt) {
  int i = blockIdx.x * blockDim.x + threadIdx.x;
  if (i < 32768) {
    int c = i & 255, k = i >> 8;
    float mu = Wmu0[k * 256 + c];
    float ev = __expf(Wlv0[k * 256 + c]);
    wgt[c * 128 + k]         = f2bf(mu);
    wgt[32768 + c * 128 + k] = f2bf(ev);
  } else if (i < 49152) {
    int i2 = i - 32768;
    int o = i2 & 63, j = i2 >> 6;
    float mu = Wmu1[j * 64 + o];
    float ev = __expf(Wlv1[j * 64 + o]);
    wgt[65536 + o * 256 + j] = f2bf(mu);
    wgt[81920 + o * 256 + j] = f2bf(mu * mu + ev);
    wgt[98304 + o * 256 + j] = f2bf(ev);
  }
}

// Fused 2-layer VB kernel, R-chunked (RC=32), 32 rows per wave.
// Each loaded B-frag is reused by 2 row-tiles -> weight L2 traffic halved.
// Layer-1 accumulates partial sums per R-chunk, so layer-0 accumulators and
// the LDS transpose buffer stay small. Zero __syncthreads (wave-private LDS).
// Block = 128 threads (2 waves). Grid covers 15626 wave-tiles of 32 rows.
__global__ __launch_bounds__(128, 2) void vb_fused(
    const float* __restrict__ X, const int* __restrict__ Xidx,
    const short* __restrict__ wgt, float* __restrict__ out) {
  // stride 40 shorts = 80 B: rows start 16B-aligned for ds_read_b128
  __shared__ short ldsM[2][2][16 * 40];
  __shared__ short ldsV[2][2][16 * 40];

  const int tid  = threadIdx.x;
  const int w    = tid >> 6;
  const int lane = tid & 63;
  const int n    = lane & 15;           // A row / B,D col within 16-tile
  const int q    = lane >> 4;           // k-octet / D row-quad
  const int row0 = (blockIdx.x * 2 + w) * 32;
  if (row0 >= N_ROWS) return;           // last block's second wave

  const short* Wmu0t  = wgt;
  const short* Wvar0t = wgt + 32768;
  const short* Wmu1t  = wgt + 65536;
  const short* A1t    = wgt + 81920;
  const short* Wvar1t = wgt + 98304;

  const f32x4 zf4 = {0.f, 0.f, 0.f, 0.f};

  // ---- load X once, pre-convert to bf16 A-frags for both row-tiles
  bf16x8 a_m[2][4], a_sq[2][4];         // [tile][kt] : 64 VGPRs
#pragma unroll
  for (int t = 0; t < 2; ++t) {
    const float* xr = X + (size_t)(row0 + t * 16 + n) * 128;
#pragma unroll
    for (int kt = 0; kt < 4; ++kt) {
      float xf[8];
      *(float4*)&xf[0] = *(const float4*)&xr[kt * 32 + q * 8];
      *(float4*)&xf[4] = *(const float4*)&xr[kt * 32 + q * 8 + 4];
#pragma unroll
      for (int u = 0; u < 8; ++u) {
        a_m[t][kt][u]  = f2bf(xf[u]);
        a_sq[t][kt][u] = f2bf(xf[u] * xf[u]);
      }
    }
  }

  // ---- layer-1 accumulators persist across R-chunks
  f32x4 accm1[2][4], accv1[2][4];
#pragma unroll
  for (int t = 0; t < 2; ++t)
#pragma unroll
    for (int c = 0; c < 4; ++c) { accm1[t][c] = zf4; accv1[t][c] = zf4; }

  for (int rc = 0; rc < 8; ++rc) {      // 8 chunks of 32 R-cols
    // -- layer 0 for this chunk: 32 rows x 32 cols
    f32x4 accm0[2][2], accv0[2][2];
#pragma unroll
    for (int t = 0; t < 2; ++t)
#pragma unroll
      for (int c = 0; c < 2; ++c) { accm0[t][c] = zf4; accv0[t][c] = zf4; }

#pragma unroll
    for (int kt = 0; kt < 4; ++kt) {
#pragma unroll
      for (int ct = 0; ct < 2; ++ct) {
        const int wb = (rc * 32 + ct * 16 + n) * 128 + kt * 32 + q * 8;
        bf16x8 bm = *(const bf16x8*)&Wmu0t[wb];
        bf16x8 bv = *(const bf16x8*)&Wvar0t[wb];
#pragma unroll
        for (int t = 0; t < 2; ++t) {
          accm0[t][ct] = __builtin_amdgcn_mfma_f32_16x16x32_bf16(a_m[t][kt],  bm, accm0[t][ct], 0, 0, 0);
          accv0[t][ct] = __builtin_amdgcn_mfma_f32_16x16x32_bf16(a_sq[t][kt], bv, accv0[t][ct], 0, 0, 0);
        }
      }
    }

    // -- gate + transpose via wave-private LDS (D layout: row=q*4+reg, col=ct*16+n)
#pragma unroll
    for (int t = 0; t < 2; ++t) {
#pragma unroll
      for (int ct = 0; ct < 2; ++ct) {
        const int c = ct * 16 + n;
#pragma unroll
        for (int reg = 0; reg < 4; ++reg) {
          float m = accm0[t][ct][reg], v = accv0[t][ct][reg];
          if (!(m > 0.f)) { m = 0.f; v = 0.f; }
          const int row = q * 4 + reg;
          ldsM[w][t][row * 40 + c] = f2bf(m);
          ldsV[w][t][row * 40 + c] = f2bf(v);
        }
      }
    }
    // same-wave RAW: compiler inserts lgkmcnt wait; no barrier needed
    bf16x8 am[2], av[2], asq[2];
#pragma unroll
    for (int t = 0; t < 2; ++t) {
      am[t] = *(const bf16x8*)&ldsM[w][t][n * 40 + q * 8];
      av[t] = *(const bf16x8*)&ldsV[w][t][n * 40 + q * 8];
#pragma unroll
      for (int u = 0; u < 8; ++u) {
        float f = bf2f(am[t][u]);
        asq[t][u] = f2bf(f * f);
      }
    }

    // -- layer 1 partial accumulate over this j-chunk (K=32 -> one MFMA step)
#pragma unroll
    for (int ct1 = 0; ct1 < 4; ++ct1) {
      const int wb1 = (ct1 * 16 + n) * 256 + rc * 32 + q * 8;
      bf16x8 b1 = *(const bf16x8*)&Wmu1t[wb1];
      bf16x8 b2 = *(const bf16x8*)&A1t[wb1];
      bf16x8 b3 = *(const bf16x8*)&Wvar1t[wb1];
#pragma unroll
      for (int t = 0; t < 2; ++t) {
        accm1[t][ct1] = __builtin_amdgcn_mfma_f32_16x16x32_bf16(am[t],  b1, accm1[t][ct1], 0, 0, 0);
        accv1[t][ct1] = __builtin_amdgcn_mfma_f32_16x16x32_bf16(av[t],  b2, accv1[t][ct1], 0, 0, 0);
        accv1[t][ct1] = __builtin_amdgcn_mfma_f32_16x16x32_bf16(asq[t], b3, accv1[t][ct1], 0, 0, 0);
      }
    }
  }

  // ---- epilogue: inv_v / m*inv_v, run-aggregated segment atomics
  float* meanp = out;                    // sum(m * inv_v)
  float* varp  = out + U_DIM * 64;       // sum(inv_v)
#pragma unroll
  for (int t = 0; t < 2; ++t) {
    int4 idx4 = *(const int4*)&Xidx[row0 + t * 16 + q * 4];
    int uid[4] = {idx4.x, idx4.y, idx4.z, idx4.w};
#pragma unroll
    for (int ct = 0; ct < 4; ++ct) {
      const int o = ct * 16 + n;
      float sm = 0.f, sv = 0.f;
      int cur = uid[0];
#pragma unroll
      for (int reg = 0; reg < 4; ++reg) {
        float v1 = fmaxf(accv1[t][ct][reg], EPSV);
        float inv = 1.0f / v1;
        float mi  = accm1[t][ct][reg] * inv;
        if (uid[reg] != cur) {
          atomicAdd(&meanp[cur * 64 + o], sm);
          atomicAdd(&varp[cur * 64 + o], sv);
          sm = 0.f; sv = 0.f; cur = uid[reg];
        }
        sm += mi; sv += inv;
      }
      atomicAdd(&meanp[cur * 64 + o], sm);
      atomicAdd(&varp[cur * 64 + o], sv);
    }
  }
}

// emb_var = 1/(sum_inv + eps); emb_mean = sum_m_inv * emb_var  (in place)
__global__ void finalize(float* __restrict__ out) {
  int i = blockIdx.x * blockDim.x + threadIdx.x;
  if (i < U_DIM * 64) {
    float s = out[U_DIM * 64 + i];
    float var = 1.0f / (s + EPSV);
    out[U_DIM * 64 + i] = var;
    out[i] = out[i] * var;
  }
}

extern "C" void kernel_launch(void* const* d_in, const int* in_sizes, int n_in,
                              void* d_out, int out_size, void* d_ws, size_t ws_size,
                              hipStream_t stream) {
  (void)in_sizes; (void)n_in; (void)out_size; (void)ws_size;
  const float* X    = (const float*)d_in[0];
  const int*   Xidx = (const int*)d_in[1];
  const float* Wmu0 = (const float*)d_in[2];
  const float* Wlv0 = (const float*)d_in[3];
  const float* Wmu1 = (const float*)d_in[4];
  const float* Wlv1 = (const float*)d_in[5];
  float* out = (float*)d_out;
  short* wgt = (short*)d_ws;            // 224 KB workspace

  hipMemsetAsync(d_out, 0, (size_t)U_DIM * 64 * 2 * sizeof(float), stream);
  prep_weights<<<192, 256, 0, stream>>>(Wmu0, Wlv0, Wmu1, Wlv1, wgt);
  // 15625 wave-tiles of 32 rows, 2 waves/block -> 7813 blocks
  vb_fused<<<7813, 128, 0, stream>>>(X, Xidx, wgt, out);
  finalize<<<(U_DIM * 64 + 255) / 256, 256, 0, stream>>>(out);
}

// Round 3
// 583.667 us; speedup vs baseline: 1.9515x; 1.3430x over previous
//
#include <hip/hip_runtime.h>
#include <stdint.h>

// Problem constants: N=500000, D_IN=128, R=256, D_OUT=64, U=10000
#define N_ROWS 500000
#define U_DIM 10000
#define EPSV 1e-8f
#define NTILES 15625          // 32-row wave-tiles

typedef __attribute__((ext_vector_type(8))) short bf16x8;   // 8 bf16 = 4 VGPRs
typedef __attribute__((ext_vector_type(4))) float f32x4;    // MFMA 16x16 accumulator

__device__ __forceinline__ short f2bf(float f) {
  unsigned u = __float_as_uint(f);
  u += 0x7fffu + ((u >> 16) & 1u);
  return (short)(u >> 16);
}
__device__ __forceinline__ float bf2f(short s) {
  return __uint_as_float(((unsigned)(unsigned short)s) << 16);
}

// Packed weight layouts in d_ws (shorts), frag-major so one wave load = 1 KB contiguous:
//   L0: [rc=8][mat=2][ct=2][kt=4][lane=64][u=8]  @ 0      (65536 shorts = 128 KB)
//   L1: [rc=8][ct1=4][mat=3][lane=64][u=8]       @ 65536  (49152 shorts =  96 KB)
// lane = q*16 + n;  element: c/o = ct*16+n,  k/j = kt*32 + q*8 + u.
__global__ void prep_weights(const float* __restrict__ Wmu0,
                             const float* __restrict__ Wlv0,
                             const float* __restrict__ Wmu1,
                             const float* __restrict__ Wlv1,
                             short* __restrict__ wgt) {
  int i = blockIdx.x * blockDim.x + threadIdx.x;
  if (i < 32768) {                       // L0 element: k = i>>8 (0..127), c = i&255
    int c = i & 255, k = i >> 8;
    int rc = c >> 5, ct = (c >> 4) & 1, n = c & 15;
    int kt = k >> 5, q = (k >> 3) & 3, u = k & 7;
    int lane = q * 16 + n;
    float mu = Wmu0[k * 256 + c];
    float ev = __expf(Wlv0[k * 256 + c]);
    wgt[((((rc * 2 + 0) * 2 + ct) * 4 + kt) * 64 + lane) * 8 + u] = f2bf(mu);
    wgt[((((rc * 2 + 1) * 2 + ct) * 4 + kt) * 64 + lane) * 8 + u] = f2bf(ev);
  } else if (i < 49152) {                // L1 element: j = (i-32768)>>6, o = &63
    int i2 = i - 32768;
    int o = i2 & 63, j = i2 >> 6;
    int rc = j >> 5, q = (j >> 3) & 3, u = j & 7;
    int ct1 = o >> 4, n = o & 15;
    int lane = q * 16 + n;
    float mu = Wmu1[j * 64 + o];
    float ev = __expf(Wlv1[j * 64 + o]);
    int b = 65536 + (((rc * 4 + ct1) * 3 + 0) * 64 + lane) * 8 + u;
    wgt[b]        = f2bf(mu);            // mat 0: mu1
    wgt[b + 512]  = f2bf(mu * mu + ev);  // mat 1: mu1^2 + var
    wgt[b + 1024] = f2bf(ev);            // mat 2: var
  }
}

// Fused 2-layer VB kernel. Block = 256 thr (4 waves), each wave 32 rows.
// Layer-0 weights staged per-rc into double-buffered LDS (ds_read_b128 frags,
// no TA); layer-1 weight frags from global, packed contiguous -> L1-resident.
// ONE __syncthreads per rc (wave skew < 1 iteration makes 2-buffer safe).
__global__ __launch_bounds__(256, 2) void vb_fused(
    const float* __restrict__ X, const int* __restrict__ Xidx,
    const short* __restrict__ wgt, float* __restrict__ out) {
  __shared__ __align__(16) short stage[2][8192];   // 2 x 16 KB L0 chunk
  __shared__ short ldsM[4][2][16 * 40];            // transpose bufs, stride 40 shorts
  __shared__ short ldsV[4][2][16 * 40];            // (rows 16B-aligned for b128)

  const int tid  = threadIdx.x;
  const int w    = tid >> 6;
  const int lane = tid & 63;
  const int n    = lane & 15;
  const int q    = lane >> 4;
  const int T    = blockIdx.x * 4 + w;             // wave-tile id
  const bool active = (T < NTILES);
  const int row0 = active ? T * 32 : (N_ROWS - 32);  // clamp: tail waves recompute dup rows

  const f32x4 zf4 = {0.f, 0.f, 0.f, 0.f};

  // ---- X prologue: load 32 rows once, pre-convert to bf16 A-frags
  bf16x8 a_m[2][4], a_sq[2][4];
#pragma unroll
  for (int t = 0; t < 2; ++t) {
    const float* xr = X + (size_t)(row0 + t * 16 + n) * 128;
#pragma unroll
    for (int kt = 0; kt < 4; ++kt) {
      float xf[8];
      *(float4*)&xf[0] = *(const float4*)&xr[kt * 32 + q * 8];
      *(float4*)&xf[4] = *(const float4*)&xr[kt * 32 + q * 8 + 4];
#pragma unroll
      for (int u = 0; u < 8; ++u) {
        a_m[t][kt][u]  = f2bf(xf[u]);
        a_sq[t][kt][u] = f2bf(xf[u] * xf[u]);
      }
    }
  }

  f32x4 accm1[2][4], accv1[2][4];
#pragma unroll
  for (int t = 0; t < 2; ++t)
#pragma unroll
    for (int c = 0; c < 4; ++c) { accm1[t][c] = zf4; accv1[t][c] = zf4; }

  // ---- staging prefetch of L0 chunk 0 (1024 uint4 per chunk, 4 per thread)
  const uint4* g4 = (const uint4*)wgt;             // L0 chunk rc at g4 + rc*1024
  uint4 u0 = g4[tid], u1 = g4[tid + 256], u2 = g4[tid + 512], u3 = g4[tid + 768];

  const int lane8 = lane * 8;

#pragma unroll
  for (int rc = 0; rc < 8; ++rc) {
    // write prefetched chunk into stage[rc&1], then barrier makes it visible
    uint4* s4 = (uint4*)&stage[rc & 1][0];
    s4[tid] = u0; s4[tid + 256] = u1; s4[tid + 512] = u2; s4[tid + 768] = u3;
    __syncthreads();
    if (rc < 7) {                                  // prefetch next chunk during compute
      const uint4* gn = g4 + (rc + 1) * 1024;
      u0 = gn[tid]; u1 = gn[tid + 256]; u2 = gn[tid + 512]; u3 = gn[tid + 768];
    }

    const short* st = &stage[rc & 1][0];

    // -- layer 0 partial: 32 rows x 32 cols, K=128, weights from LDS
    f32x4 accm0[2][2], accv0[2][2];
#pragma unroll
    for (int t = 0; t < 2; ++t)
#pragma unroll
      for (int c = 0; c < 2; ++c) { accm0[t][c] = zf4; accv0[t][c] = zf4; }

#pragma unroll
    for (int kt = 0; kt < 4; ++kt) {
#pragma unroll
      for (int ct = 0; ct < 2; ++ct) {
        bf16x8 bm = *(const bf16x8*)&st[((0 * 2 + ct) * 4 + kt) * 512 + lane8];
        bf16x8 bv = *(const bf16x8*)&st[((1 * 2 + ct) * 4 + kt) * 512 + lane8];
#pragma unroll
        for (int t = 0; t < 2; ++t) {
          accm0[t][ct] = __builtin_amdgcn_mfma_f32_16x16x32_bf16(a_m[t][kt],  bm, accm0[t][ct], 0, 0, 0);
          accv0[t][ct] = __builtin_amdgcn_mfma_f32_16x16x32_bf16(a_sq[t][kt], bv, accv0[t][ct], 0, 0, 0);
        }
      }
    }

    // -- gate + transpose via wave-private LDS (D: row=q*4+reg, col=ct*16+n)
#pragma unroll
    for (int t = 0; t < 2; ++t) {
#pragma unroll
      for (int ct = 0; ct < 2; ++ct) {
        const int c = ct * 16 + n;
#pragma unroll
        for (int reg = 0; reg < 4; ++reg) {
          float m = accm0[t][ct][reg], v = accv0[t][ct][reg];
          if (!(m > 0.f)) { m = 0.f; v = 0.f; }
          const int row = q * 4 + reg;
          ldsM[w][t][row * 40 + c] = f2bf(m);
          ldsV[w][t][row * 40 + c] = f2bf(v);
        }
      }
    }
    bf16x8 am[2], av[2], asq[2];
#pragma unroll
    for (int t = 0; t < 2; ++t) {
      am[t] = *(const bf16x8*)&ldsM[w][t][n * 40 + q * 8];
      av[t] = *(const bf16x8*)&ldsV[w][t][n * 40 + q * 8];
#pragma unroll
      for (int u = 0; u < 8; ++u) {
        float f = bf2f(am[t][u]);
        asq[t][u] = f2bf(f * f);
      }
    }

    // -- layer 1 partial: weights from global (packed 1 KB frags, L1-resident)
    const short* l1b = wgt + 65536 + rc * 6144 + lane8;
#pragma unroll
    for (int ct1 = 0; ct1 < 4; ++ct1) {
      const short* fb = l1b + ct1 * 1536;
      bf16x8 b1 = *(const bf16x8*)&fb[0];
      bf16x8 b2 = *(const bf16x8*)&fb[512];
      bf16x8 b3 = *(const bf16x8*)&fb[1024];
#pragma unroll
      for (int t = 0; t < 2; ++t) {
        accm1[t][ct1] = __builtin_amdgcn_mfma_f32_16x16x32_bf16(am[t],  b1, accm1[t][ct1], 0, 0, 0);
        accv1[t][ct1] = __builtin_amdgcn_mfma_f32_16x16x32_bf16(av[t],  b2, accv1[t][ct1], 0, 0, 0);
        accv1[t][ct1] = __builtin_amdgcn_mfma_f32_16x16x32_bf16(asq[t], b3, accv1[t][ct1], 0, 0, 0);
      }
    }
  }

  // ---- epilogue: run-aggregated segment atomics (tail-dup waves skip)
  if (!active) return;
  float* meanp = out;
  float* varp  = out + U_DIM * 64;
#pragma unroll
  for (int t = 0; t < 2; ++t) {
    int4 idx4 = *(const int4*)&Xidx[row0 + t * 16 + q * 4];
    int uid[4] = {idx4.x, idx4.y, idx4.z, idx4.w};
#pragma unroll
    for (int ct = 0; ct < 4; ++ct) {
      const int o = ct * 16 + n;
      float sm = 0.f, sv = 0.f;
      int cur = uid[0];
#pragma unroll
      for (int reg = 0; reg < 4; ++reg) {
        float v1 = fmaxf(accv1[t][ct][reg], EPSV);
        float inv = 1.0f / v1;
        float mi  = accm1[t][ct][reg] * inv;
        if (uid[reg] != cur) {
          atomicAdd(&meanp[cur * 64 + o], sm);
          atomicAdd(&varp[cur * 64 + o], sv);
          sm = 0.f; sv = 0.f; cur = uid[reg];
        }
        sm += mi; sv += inv;
      }
      atomicAdd(&meanp[cur * 64 + o], sm);
      atomicAdd(&varp[cur * 64 + o], sv);
    }
  }
}

// emb_var = 1/(sum_inv + eps); emb_mean = sum_m_inv * emb_var  (in place)
__global__ void finalize(float* __restrict__ out) {
  int i = blockIdx.x * blockDim.x + threadIdx.x;
  if (i < U_DIM * 64) {
    float s = out[U_DIM * 64 + i];
    float var = 1.0f / (s + EPSV);
    out[U_DIM * 64 + i] = var;
    out[i] = out[i] * var;
  }
}

extern "C" void kernel_launch(void* const* d_in, const int* in_sizes, int n_in,
                              void* d_out, int out_size, void* d_ws, size_t ws_size,
                              hipStream_t stream) {
  (void)in_sizes; (void)n_in; (void)out_size; (void)ws_size;
  const float* X    = (const float*)d_in[0];
  const int*   Xidx = (const int*)d_in[1];
  const float* Wmu0 = (const float*)d_in[2];
  const float* Wlv0 = (const float*)d_in[3];
  const float* Wmu1 = (const float*)d_in[4];
  const float* Wlv1 = (const float*)d_in[5];
  float* out = (float*)d_out;
  short* wgt = (short*)d_ws;            // 224 KB workspace (packed weights)

  hipMemsetAsync(d_out, 0, (size_t)U_DIM * 64 * 2 * sizeof(float), stream);
  prep_weights<<<192, 256, 0, stream>>>(Wmu0, Wlv0, Wmu1, Wlv1, wgt);
  // 15625 wave-tiles / 4 per block -> 3907 blocks (tail waves clamped+guarded)
  vb_fused<<<3907, 256, 0, stream>>>(X, Xidx, wgt, out);
  finalize<<<(U_DIM * 64 + 255) / 256, 256, 0, stream>>>(out);
}

// Round 5
// 556.359 us; speedup vs baseline: 2.0473x; 1.0491x over previous
//
#include <hip/hip_runtime.h>
#include <stdint.h>

// Problem constants: N=500000, D_IN=128, R=256, D_OUT=64, U=10000
#define N_ROWS 500000
#define U_DIM 10000
#define EPSV 1e-8f
#define NT16 31250            // 16-row wave-tiles

typedef __attribute__((ext_vector_type(8))) short bf16x8;   // 8 bf16 = 4 VGPRs
typedef __attribute__((ext_vector_type(4))) float f32x4;    // MFMA 16x16 accumulator

__device__ __forceinline__ short f2bf(float f) {
  unsigned u = __float_as_uint(f);
  u += 0x7fffu + ((u >> 16) & 1u);
  return (short)(u >> 16);
}
__device__ __forceinline__ float bf2f(short s) {
  return __uint_as_float(((unsigned)(unsigned short)s) << 16);
}

// Packed weight layouts in d_ws (shorts), frag-major (one wave load = 1 KB):
//   L0: [rc=8][mat=2][ct=2][kt=4][lane=64][u=8]  @ 0      (128 KB; 16 KB/rc chunk)
//   L1: [rc=8][ct1=4][mat=3][lane=64][u=8]       @ 65536  (96 KB)
// lane = q*16 + n;  element: c/o = ct*16+n,  k/j = kt*32 + q*8 + u.
__global__ void prep_weights(const float* __restrict__ Wmu0,
                             const float* __restrict__ Wlv0,
                             const float* __restrict__ Wmu1,
                             const float* __restrict__ Wlv1,
                             short* __restrict__ wgt) {
  int i = blockIdx.x * blockDim.x + threadIdx.x;
  if (i < 32768) {                       // L0 element: k = i>>8 (0..127), c = i&255
    int c = i & 255, k = i >> 8;
    int rc = c >> 5, ct = (c >> 4) & 1, n = c & 15;
    int kt = k >> 5, q = (k >> 3) & 3, u = k & 7;
    int lane = q * 16 + n;
    float mu = Wmu0[k * 256 + c];
    float ev = __expf(Wlv0[k * 256 + c]);
    wgt[((((rc * 2 + 0) * 2 + ct) * 4 + kt) * 64 + lane) * 8 + u] = f2bf(mu);
    wgt[((((rc * 2 + 1) * 2 + ct) * 4 + kt) * 64 + lane) * 8 + u] = f2bf(ev);
  } else if (i < 49152) {                // L1 element: j = (i-32768)>>6, o = &63
    int i2 = i - 32768;
    int o = i2 & 63, j = i2 >> 6;
    int rc = j >> 5, q = (j >> 3) & 3, u = j & 7;
    int ct1 = o >> 4, n = o & 15;
    int lane = q * 16 + n;
    float mu = Wmu1[j * 64 + o];
    float ev = __expf(Wlv1[j * 64 + o]);
    int b = 65536 + (((rc * 4 + ct1) * 3 + 0) * 64 + lane) * 8 + u;
    wgt[b]        = f2bf(mu);            // mat 0: mu1
    wgt[b + 512]  = f2bf(mu * mu + ev);  // mat 1: mu1^2 + var
    wgt[b + 1024] = f2bf(ev);            // mat 2: var
  }
}

// Fused 2-layer VB kernel. Block = 256 thr (4 waves), each wave ONE 16-row tile.
// L0 weights staged per-rc via global_load_lds (async, double-buffered, one
// barrier per rc). R4 BUG FIX: a 16 KB chunk needs FOUR 16B-wide issues per
// thread (256 thr x 16 B = 4 KB per issue); R4 issued one -> 12 KB of stage
// was uninitialized LDS -> NaN. Segment s: global/LDS offset s*4096 + w*1024
// (+ lane*16 added by HW; LDS base must be wave-uniform per m104/m108).
__global__ __launch_bounds__(256, 3) void vb_fused(
    const float* __restrict__ X, const int* __restrict__ Xidx,
    const short* __restrict__ wgt, float* __restrict__ out) {
  __shared__ __align__(16) short stage[2][8192];   // 2 x 16 KB L0 chunk
  __shared__ __align__(16) short ldsM[4][16 * 40]; // per-wave transpose, stride 40
  __shared__ __align__(16) short ldsV[4][16 * 40];

  const int tid  = threadIdx.x;
  const int w    = tid >> 6;
  const int lane = tid & 63;
  const int n    = lane & 15;
  const int q    = lane >> 4;
  const int T    = blockIdx.x * 4 + w;             // wave-tile id
  const bool active = (T < NT16);
  const int row0 = active ? T * 16 : (N_ROWS - 16);  // tail waves: dup rows, no atomics

  const f32x4 zf4 = {0.f, 0.f, 0.f, 0.f};
  const int lane8 = lane * 8;

  // ---- X prologue: 16 rows once, pre-convert to bf16 A-frags (32 VGPRs)
  bf16x8 a_m[4], a_sq[4];
  {
    const float* xr = X + (size_t)(row0 + n) * 128;
#pragma unroll
    for (int kt = 0; kt < 4; ++kt) {
      float xf[8];
      *(float4*)&xf[0] = *(const float4*)&xr[kt * 32 + q * 8];
      *(float4*)&xf[4] = *(const float4*)&xr[kt * 32 + q * 8 + 4];
#pragma unroll
      for (int u = 0; u < 8; ++u) {
        a_m[kt][u]  = f2bf(xf[u]);
        a_sq[kt][u] = f2bf(xf[u] * xf[u]);
      }
    }
  }

  f32x4 accm1[4], accv1[4];
#pragma unroll
  for (int c = 0; c < 4; ++c) { accm1[c] = zf4; accv1[c] = zf4; }

  // ---- async staging: 4 segments x (256 thr x 16 B) = 16 KB per rc-chunk.
  const char* gbase = (const char*)wgt;
#define ISSUE_STAGE(rc_, buf_)                                                 \
  do {                                                                         \
    _Pragma("unroll")                                                          \
    for (int s_ = 0; s_ < 4; ++s_) {                                           \
      __builtin_amdgcn_global_load_lds(                                        \
          (const __attribute__((address_space(1))) unsigned int*)              \
              (gbase + (rc_) * 16384 + s_ * 4096 + tid * 16),                  \
          (__attribute__((address_space(3))) unsigned int*)                    \
              ((char*)&stage[buf_][0] + s_ * 4096 + (w << 10)),                \
          16, 0, 0);                                                           \
    }                                                                          \
  } while (0)

  ISSUE_STAGE(0, 0);

#pragma unroll
  for (int rc = 0; rc < 8; ++rc) {
    // barrier: compiler drains vmcnt(0) before s_barrier -> stage[rc&1] is
    // complete+visible; all waves have finished reading stage[(rc+1)&1]
    // (their reads were iteration rc-1, lgkmcnt drained before the barrier).
    __syncthreads();
    if (rc < 7) ISSUE_STAGE(rc + 1, (rc + 1) & 1);

    const short* st = &stage[rc & 1][0];

    // -- layer 0 partial: 16 rows x 32 cols, K=128, weights from LDS
    f32x4 accm0[2], accv0[2];
    accm0[0] = zf4; accm0[1] = zf4; accv0[0] = zf4; accv0[1] = zf4;
#pragma unroll
    for (int kt = 0; kt < 4; ++kt) {
#pragma unroll
      for (int ct = 0; ct < 2; ++ct) {
        bf16x8 bm = *(const bf16x8*)&st[((0 * 2 + ct) * 4 + kt) * 512 + lane8];
        bf16x8 bv = *(const bf16x8*)&st[((1 * 2 + ct) * 4 + kt) * 512 + lane8];
        accm0[ct] = __builtin_amdgcn_mfma_f32_16x16x32_bf16(a_m[kt],  bm, accm0[ct], 0, 0, 0);
        accv0[ct] = __builtin_amdgcn_mfma_f32_16x16x32_bf16(a_sq[kt], bv, accv0[ct], 0, 0, 0);
      }
    }

    // -- gate + transpose via wave-private LDS (D: row=q*4+reg, col=ct*16+n)
#pragma unroll
    for (int ct = 0; ct < 2; ++ct) {
      const int c = ct * 16 + n;
#pragma unroll
      for (int reg = 0; reg < 4; ++reg) {
        float m = accm0[ct][reg], v = accv0[ct][reg];
        if (!(m > 0.f)) { m = 0.f; v = 0.f; }
        const int row = q * 4 + reg;
        ldsM[w][row * 40 + c] = f2bf(m);
        ldsV[w][row * 40 + c] = f2bf(v);
      }
    }
    // same-wave RAW: compiler inserts lgkmcnt wait; no barrier needed
    bf16x8 am = *(const bf16x8*)&ldsM[w][n * 40 + q * 8];
    bf16x8 av = *(const bf16x8*)&ldsV[w][n * 40 + q * 8];
    bf16x8 asq;
#pragma unroll
    for (int u = 0; u < 8; ++u) {
      float f = bf2f(am[u]);
      asq[u] = f2bf(f * f);
    }

    // -- layer 1 partial: weights from global (packed 1 KB frags, L1-resident)
    const short* l1b = wgt + 65536 + rc * 6144 + lane8;
#pragma unroll
    for (int ct1 = 0; ct1 < 4; ++ct1) {
      const short* fb = l1b + ct1 * 1536;
      bf16x8 b1 = *(const bf16x8*)&fb[0];
      bf16x8 b2 = *(const bf16x8*)&fb[512];
      bf16x8 b3 = *(const bf16x8*)&fb[1024];
      accm1[ct1] = __builtin_amdgcn_mfma_f32_16x16x32_bf16(am,  b1, accm1[ct1], 0, 0, 0);
      accv1[ct1] = __builtin_amdgcn_mfma_f32_16x16x32_bf16(av,  b2, accv1[ct1], 0, 0, 0);
      accv1[ct1] = __builtin_amdgcn_mfma_f32_16x16x32_bf16(asq, b3, accv1[ct1], 0, 0, 0);
    }
  }
#undef ISSUE_STAGE

  // ---- epilogue: run-aggregated segment atomics (tail-dup waves skip)
  if (!active) return;
  float* meanp = out;
  float* varp  = out + U_DIM * 64;
  int4 idx4 = *(const int4*)&Xidx[row0 + q * 4];
  int uid[4] = {idx4.x, idx4.y, idx4.z, idx4.w};
#pragma unroll
  for (int ct = 0; ct < 4; ++ct) {
    const int o = ct * 16 + n;
    float sm = 0.f, sv = 0.f;
    int cur = uid[0];
#pragma unroll
    for (int reg = 0; reg < 4; ++reg) {
      float v1 = fmaxf(accv1[ct][reg], EPSV);
      float inv = 1.0f / v1;
      float mi  = accm1[ct][reg] * inv;
      if (uid[reg] != cur) {
        atomicAdd(&meanp[cur * 64 + o], sm);
        atomicAdd(&varp[cur * 64 + o], sv);
        sm = 0.f; sv = 0.f; cur = uid[reg];
      }
      sm += mi; sv += inv;
    }
    atomicAdd(&meanp[cur * 64 + o], sm);
    atomicAdd(&varp[cur * 64 + o], sv);
  }
}

// emb_var = 1/(sum_inv + eps); emb_mean = sum_m_inv * emb_var  (in place)
__global__ void finalize(float* __restrict__ out) {
  int i = blockIdx.x * blockDim.x + threadIdx.x;
  if (i < U_DIM * 64) {
    float s = out[U_DIM * 64 + i];
    float var = 1.0f / (s + EPSV);
    out[U_DIM * 64 + i] = var;
    out[i] = out[i] * var;
  }
}

extern "C" void kernel_launch(void* const* d_in, const int* in_sizes, int n_in,
                              void* d_out, int out_size, void* d_ws, size_t ws_size,
                              hipStream_t stream) {
  (void)in_sizes; (void)n_in; (void)out_size; (void)ws_size;
  const float* X    = (const float*)d_in[0];
  const int*   Xidx = (const int*)d_in[1];
  const float* Wmu0 = (const float*)d_in[2];
  const float* Wlv0 = (const float*)d_in[3];
  const float* Wmu1 = (const float*)d_in[4];
  const float* Wlv1 = (const float*)d_in[5];
  float* out = (float*)d_out;
  short* wgt = (short*)d_ws;            // 224 KB workspace (packed weights)

  hipMemsetAsync(d_out, 0, (size_t)U_DIM * 64 * 2 * sizeof(float), stream);
  prep_weights<<<192, 256, 0, stream>>>(Wmu0, Wlv0, Wmu1, Wlv1, wgt);
  // 31250 16-row wave-tiles / 4 per block -> 7813 blocks (tail clamped+guarded)
  vb_fused<<<7813, 256, 0, stream>>>(X, Xidx, wgt, out);
  finalize<<<(U_DIM * 64 + 255) / 256, 256, 0, stream>>>(out);
}